// Round 5
// baseline (518.199 us; speedup 1.0000x reference)
//
#include <hip/hip_runtime.h>

typedef __bf16 bf16x8 __attribute__((ext_vector_type(8)));
typedef float  f32x4  __attribute__((ext_vector_type(4)));
typedef unsigned int u32x4 __attribute__((ext_vector_type(4)));

#define B_   2
#define N_   512
#define ND_  256
#define ED_  64
#define NH_  8
#define DH_  32

static __device__ __forceinline__ unsigned pack_bf16(float a, float b) {
    unsigned short ua = __builtin_bit_cast(unsigned short, (__bf16)a);
    unsigned short ub = __builtin_bit_cast(unsigned short, (__bf16)b);
    return (unsigned)ua | ((unsigned)ub << 16);
}

// ---------------- prep kernel 1: edge-weight fp32 -> bf16 ----------------
__global__ __launch_bounds__(256) void cvt_w_kernel(
    const float* __restrict__ wq, const float* __restrict__ wk,
    const float* __restrict__ wv, unsigned short* __restrict__ w16)
{
    int id = blockIdx.x * 256 + threadIdx.x;          // 0..49151
    const float* src = (id < 16384) ? wq : (id < 32768 ? wk : wv);
    int idx = id & 16383;
    w16[id] = __builtin_bit_cast(unsigned short, (__bf16)src[idx]);
}

// ------- prep kernel 2: node projections, folded biases, HEAD-SPLIT ------
__global__ __launch_bounds__(256) void qkv_kernel(
    const float* __restrict__ node,
    const float* __restrict__ Wq, const float* __restrict__ bq,
    const float* __restrict__ Wk, const float* __restrict__ bk,
    const float* __restrict__ Wv, const float* __restrict__ bv,
    const float* __restrict__ beq, const float* __restrict__ bek,
    const float* __restrict__ bev,
    float* __restrict__ Qh, float* __restrict__ Kh, float* __restrict__ Vh)
{
    __shared__ float xs[4][ND_];
    const int c  = threadIdx.x;
    const int g0 = blockIdx.x * 4;
    #pragma unroll
    for (int rr = 0; rr < 4; rr++) xs[rr][c] = node[(size_t)(g0 + rr) * ND_ + c];
    __syncthreads();

    float aq[4] = {}, ak[4] = {}, av[4] = {};
    const float4* wqr = reinterpret_cast<const float4*>(Wq + (size_t)c * ND_);
    const float4* wkr = reinterpret_cast<const float4*>(Wk + (size_t)c * ND_);
    const float4* wvr = reinterpret_cast<const float4*>(Wv + (size_t)c * ND_);
    for (int k4 = 0; k4 < ND_ / 4; k4++) {
        float4 wqv = wqr[k4], wkv = wkr[k4], wvv = wvr[k4];
        #pragma unroll
        for (int rr = 0; rr < 4; rr++) {
            const float4 x = *reinterpret_cast<const float4*>(&xs[rr][k4 * 4]);
            aq[rr] += x.x*wqv.x + x.y*wqv.y + x.z*wqv.z + x.w*wqv.w;
            ak[rr] += x.x*wkv.x + x.y*wkv.y + x.z*wkv.z + x.w*wkv.w;
            av[rr] += x.x*wvv.x + x.y*wvv.y + x.z*wvv.z + x.w*wvv.w;
        }
    }
    const float bqv = bq[c] + beq[c];
    const float bkv = bk[c] + bek[c];
    const float bvv = bv[c] + bev[c];
    const int h = c >> 5, d = c & 31;
    #pragma unroll
    for (int rr = 0; rr < 4; rr++) {
        const int g  = g0 + rr;
        const int bb = g >> 9, ii = g & (N_ - 1);
        size_t o = ((size_t)(bb * NH_ + h) * N_ + ii) * DH_ + d;
        Qh[o] = aq[rr] + bqv;
        Kh[o] = ak[rr] + bkv;
        Vh[o] = av[rr] + bvv;
    }
}

// --------- main kernel: wave-owned (b, i-pair, 32-j slice), NO barriers ---
// 4 waves/block (private LDS segments). Wave: stage 2x32 e-rows (16 coalesced
// dwordx4 in flight), then h-loop over all 8 heads; K/V C-operand loads
// shared across the i-pair; unnormalized o/l accumulated via atomics.
__global__ __launch_bounds__(256, 4) void attn_kernel(
    const float* __restrict__ edge,
    const float* __restrict__ Qh, const float* __restrict__ Kh,
    const float* __restrict__ Vh, const unsigned short* __restrict__ W16,
    float* __restrict__ o_acc, float* __restrict__ l_out)
{
    __shared__ unsigned short lds_[4][64 * 72];

    const int tid  = threadIdx.x;
    const int lane = tid & 63;
    const int w    = tid >> 6;
    const int q4   = lane >> 4;
    const int l15  = lane & 15;
    const int gw   = blockIdx.x * 4 + w;
    const int pi   = gw >> 4;            // (b, i-pair): 0..511
    const int sl   = gw & 15;            // 32-row j-slice
    const int b    = pi >> 8;
    const int i0   = (pi & 255) * 2;

    unsigned short* myl = lds_[w];

    // ---- stage 2 x 32 e-rows (16 KB) with 16 outstanding dwordx4 loads ----
    const float4* ep0 = reinterpret_cast<const float4*>(
        edge + ((size_t)(b * N_ + i0) * N_ + sl * 32) * ED_);
    const float4* ep1 = reinterpret_cast<const float4*>(
        edge + ((size_t)(b * N_ + i0 + 1) * N_ + sl * 32) * ED_);
    float4 g[16];
    #pragma unroll
    for (int t = 0; t < 8; t++) g[t] = ep0[lane + t * 64];
    #pragma unroll
    for (int t = 0; t < 8; t++) g[8 + t] = ep1[lane + t * 64];
    #pragma unroll
    for (int t = 0; t < 16; t++) {
        const int flat = lane + (t & 7) * 64;              // float4 index in 8KB half
        const int row  = (t >> 3) * 32 + (flat >> 4);      // 0..63
        const int c4   = flat & 15;
        uint2 v = {pack_bf16(g[t].x, g[t].y), pack_bf16(g[t].z, g[t].w)};
        *reinterpret_cast<uint2*>(myl + row * 72 + c4 * 4) = v;
    }

    const float scale = 0.17677669529663687f;   // 1/sqrt(32)

    #pragma unroll 1
    for (int h = 0; h < NH_; h++) {
        const int bh = b * NH_ + h;
        bf16x8 wf[3][2][2];
        #pragma unroll
        for (int m = 0; m < 3; m++)
            #pragma unroll
            for (int hf = 0; hf < 2; hf++)
                #pragma unroll
                for (int ks = 0; ks < 2; ks++)
                    wf[m][hf][ks] = __builtin_bit_cast(bf16x8,
                        *reinterpret_cast<const u32x4*>(
                        W16 + m * (ND_ * ED_) + (h * DH_ + hf * 16 + l15) * ED_
                            + ks * 32 + q4 * 8));

        const float* Q0 = Qh + ((size_t)bh * N_ + i0) * DH_;
        const f32x4 Cq00 = *reinterpret_cast<const f32x4*>(Q0 + q4 * 4);
        const f32x4 Cq01 = *reinterpret_cast<const f32x4*>(Q0 + 16 + q4 * 4);
        const f32x4 Cq10 = *reinterpret_cast<const f32x4*>(Q0 + DH_ + q4 * 4);
        const f32x4 Cq11 = *reinterpret_cast<const f32x4*>(Q0 + DH_ + 16 + q4 * 4);
        const float* Kb = Kh + (size_t)bh * N_ * DH_;
        const float* Vb = Vh + (size_t)bh * N_ * DH_;

        f32x4 oA0 = {0,0,0,0}, oA1 = {0,0,0,0};   // i0
        f32x4 oB0 = {0,0,0,0}, oB1 = {0,0,0,0};   // i1
        float lsA = 0.f, lsB = 0.f;

        #pragma unroll
        for (int s = 0; s < 2; s++) {
            const int j = sl * 32 + s * 16 + l15;
            const float* Krow = Kb + (size_t)j * DH_;
            const float* Vrow = Vb + (size_t)j * DH_;
            const f32x4 Ck0 = *reinterpret_cast<const f32x4*>(Krow + q4 * 4);
            const f32x4 Ck1 = *reinterpret_cast<const f32x4*>(Krow + 16 + q4 * 4);
            const f32x4 Cv0 = *reinterpret_cast<const f32x4*>(Vrow + q4 * 4);
            const f32x4 Cv1 = *reinterpret_cast<const f32x4*>(Vrow + 16 + q4 * 4);

            #pragma unroll
            for (int il = 0; il < 2; il++) {
                const unsigned short* arow =
                    myl + (il * 32 + s * 16 + l15) * 72 + q4 * 8;
                const bf16x8 a0 = __builtin_bit_cast(bf16x8,
                    *reinterpret_cast<const u32x4*>(arow));
                const bf16x8 a1 = __builtin_bit_cast(bf16x8,
                    *reinterpret_cast<const u32x4*>(arow + 32));
                const f32x4 cq0 = il ? Cq10 : Cq00;
                const f32x4 cq1 = il ? Cq11 : Cq01;

                f32x4 eq0 = __builtin_amdgcn_mfma_f32_16x16x32_bf16(wf[0][0][0], a0, cq0, 0, 0, 0);
                f32x4 eq1 = __builtin_amdgcn_mfma_f32_16x16x32_bf16(wf[0][1][0], a0, cq1, 0, 0, 0);
                f32x4 ek0 = __builtin_amdgcn_mfma_f32_16x16x32_bf16(wf[1][0][0], a0, Ck0, 0, 0, 0);
                f32x4 ek1 = __builtin_amdgcn_mfma_f32_16x16x32_bf16(wf[1][1][0], a0, Ck1, 0, 0, 0);
                f32x4 ev0 = __builtin_amdgcn_mfma_f32_16x16x32_bf16(wf[2][0][0], a0, Cv0, 0, 0, 0);
                f32x4 ev1 = __builtin_amdgcn_mfma_f32_16x16x32_bf16(wf[2][1][0], a0, Cv1, 0, 0, 0);
                eq0 = __builtin_amdgcn_mfma_f32_16x16x32_bf16(wf[0][0][1], a1, eq0, 0, 0, 0);
                eq1 = __builtin_amdgcn_mfma_f32_16x16x32_bf16(wf[0][1][1], a1, eq1, 0, 0, 0);
                ek0 = __builtin_amdgcn_mfma_f32_16x16x32_bf16(wf[1][0][1], a1, ek0, 0, 0, 0);
                ek1 = __builtin_amdgcn_mfma_f32_16x16x32_bf16(wf[1][1][1], a1, ek1, 0, 0, 0);
                ev0 = __builtin_amdgcn_mfma_f32_16x16x32_bf16(wf[2][0][1], a1, ev0, 0, 0, 0);
                ev1 = __builtin_amdgcn_mfma_f32_16x16x32_bf16(wf[2][1][1], a1, ev1, 0, 0, 0);

                float t = eq0[0]*ek0[0] + eq0[1]*ek0[1] + eq0[2]*ek0[2] + eq0[3]*ek0[3]
                        + eq1[0]*ek1[0] + eq1[1]*ek1[1] + eq1[2]*ek1[2] + eq1[3]*ek1[3];
                t += __shfl_xor(t, 16, 64);
                t += __shfl_xor(t, 32, 64);
                const float p = __expf(fmaf(t, scale, -4.f));   // shift cancels in norm

                if (il == 0) { lsA += p; oA0 += ev0 * p; oA1 += ev1 * p; }
                else         { lsB += p; oB0 += ev0 * p; oB1 += ev1 * p; }
            }
        }

        // reduce over the 16 j-lanes (masks 1..8 stay within each quad)
        #pragma unroll
        for (int mask = 1; mask <= 8; mask <<= 1) {
            lsA += __shfl_xor(lsA, mask, 64);
            lsB += __shfl_xor(lsB, mask, 64);
            #pragma unroll
            for (int r = 0; r < 4; r++) {
                oA0[r] += __shfl_xor(oA0[r], mask, 64);
                oA1[r] += __shfl_xor(oA1[r], mask, 64);
                oB0[r] += __shfl_xor(oB0[r], mask, 64);
                oB1[r] += __shfl_xor(oB1[r], mask, 64);
            }
        }
        if (l15 == 0) {
            float* rowA = o_acc + (size_t)(b * N_ + i0) * ND_ + h * DH_ + q4 * 4;
            float* rowB = rowA + ND_;
            #pragma unroll
            for (int r = 0; r < 4; r++) {
                atomicAdd(rowA + r,      oA0[r]);
                atomicAdd(rowA + 16 + r, oA1[r]);
                atomicAdd(rowB + r,      oB0[r]);
                atomicAdd(rowB + 16 + r, oB1[r]);
            }
            if (q4 == 0) {
                atomicAdd(l_out + (size_t)(b * N_ + i0) * NH_ + h, lsA);
                atomicAdd(l_out + (size_t)(b * N_ + i0 + 1) * NH_ + h, lsB);
            }
        }
    }
}

// ---------------- epilogue: divide by softmax denominator ----------------
__global__ __launch_bounds__(256) void norm_kernel(
    float* __restrict__ out, const float* __restrict__ l)
{
    const int idx = blockIdx.x * 256 + threadIdx.x;   // 0..262143
    const int bi  = idx >> 8;
    const int h   = (idx & 255) >> 5;
    out[idx] /= l[bi * NH_ + h];
}

extern "C" void kernel_launch(void* const* d_in, const int* in_sizes, int n_in,
                              void* d_out, int out_size, void* d_ws, size_t ws_size,
                              hipStream_t stream) {
    const float* node = (const float*)d_in[0];
    const float* edge = (const float*)d_in[1];
    const float* Wnq  = (const float*)d_in[2];
    const float* bnq  = (const float*)d_in[3];
    const float* Wnk  = (const float*)d_in[4];
    const float* bnk  = (const float*)d_in[5];
    const float* Wnv  = (const float*)d_in[6];
    const float* bnv  = (const float*)d_in[7];
    const float* Weq  = (const float*)d_in[8];
    const float* beq  = (const float*)d_in[9];
    const float* Wek  = (const float*)d_in[10];
    const float* bek  = (const float*)d_in[11];
    const float* Wev  = (const float*)d_in[12];
    const float* bev  = (const float*)d_in[13];

    char* ws = (char*)d_ws;
    unsigned short* W16 = (unsigned short*)ws;              // 96 KB (128 KB slot)
    float* Qh = (float*)(ws + 131072);                      // 1 MB each
    float* Kh = Qh + (size_t)B_ * N_ * ND_;
    float* Vh = Kh + (size_t)B_ * N_ * ND_;
    float* l_buf = Vh + (size_t)B_ * N_ * ND_;              // 32 KB
    float* out = (float*)d_out;

    cvt_w_kernel<<<192, 256, 0, stream>>>(Weq, Wek, Wev, W16);
    qkv_kernel<<<(B_ * N_) / 4, 256, 0, stream>>>(node, Wnq, bnq, Wnk, bnk, Wnv, bnv,
                                                  beq, bek, bev, Qh, Kh, Vh);
    hipMemsetAsync(out, 0, (size_t)B_ * N_ * ND_ * sizeof(float), stream);
    hipMemsetAsync(l_buf, 0, (size_t)B_ * N_ * NH_ * sizeof(float), stream);
    attn_kernel<<<2048, 256, 0, stream>>>(edge, Qh, Kh, Vh, W16, out, l_buf);
    norm_kernel<<<(B_ * N_ * ND_) / 256, 256, 0, stream>>>(out, l_buf);
}

// Round 6
// 421.084 us; speedup vs baseline: 1.2306x; 1.2306x over previous
//
#include <hip/hip_runtime.h>

typedef __bf16 bf16x8 __attribute__((ext_vector_type(8)));
typedef float  f32x4  __attribute__((ext_vector_type(4)));
typedef unsigned int u32x4 __attribute__((ext_vector_type(4)));

#define B_   2
#define N_   512
#define ND_  256
#define ED_  64
#define NH_  8
#define DH_  32

static __device__ __forceinline__ unsigned pack_bf16(float a, float b) {
    unsigned short ua = __builtin_bit_cast(unsigned short, (__bf16)a);
    unsigned short ub = __builtin_bit_cast(unsigned short, (__bf16)b);
    return (unsigned)ua | ((unsigned)ub << 16);
}

// ---------------- prep kernel 1: edge-weight fp32 -> bf16 ----------------
__global__ __launch_bounds__(256) void cvt_w_kernel(
    const float* __restrict__ wq, const float* __restrict__ wk,
    const float* __restrict__ wv, unsigned short* __restrict__ w16)
{
    int id = blockIdx.x * 256 + threadIdx.x;          // 0..49151
    const float* src = (id < 16384) ? wq : (id < 32768 ? wk : wv);
    int idx = id & 16383;
    w16[id] = __builtin_bit_cast(unsigned short, (__bf16)src[idx]);
}

// ------- prep kernel 2: node projections, folded biases, HEAD-SPLIT ------
__global__ __launch_bounds__(256) void qkv_kernel(
    const float* __restrict__ node,
    const float* __restrict__ Wq, const float* __restrict__ bq,
    const float* __restrict__ Wk, const float* __restrict__ bk,
    const float* __restrict__ Wv, const float* __restrict__ bv,
    const float* __restrict__ beq, const float* __restrict__ bek,
    const float* __restrict__ bev,
    float* __restrict__ Qh, float* __restrict__ Kh, float* __restrict__ Vh)
{
    __shared__ float xs[4][ND_];
    const int c  = threadIdx.x;
    const int g0 = blockIdx.x * 4;
    #pragma unroll
    for (int rr = 0; rr < 4; rr++) xs[rr][c] = node[(size_t)(g0 + rr) * ND_ + c];
    __syncthreads();

    float aq[4] = {}, ak[4] = {}, av[4] = {};
    const float4* wqr = reinterpret_cast<const float4*>(Wq + (size_t)c * ND_);
    const float4* wkr = reinterpret_cast<const float4*>(Wk + (size_t)c * ND_);
    const float4* wvr = reinterpret_cast<const float4*>(Wv + (size_t)c * ND_);
    for (int k4 = 0; k4 < ND_ / 4; k4++) {
        float4 wqv = wqr[k4], wkv = wkr[k4], wvv = wvr[k4];
        #pragma unroll
        for (int rr = 0; rr < 4; rr++) {
            const float4 x = *reinterpret_cast<const float4*>(&xs[rr][k4 * 4]);
            aq[rr] += x.x*wqv.x + x.y*wqv.y + x.z*wqv.z + x.w*wqv.w;
            ak[rr] += x.x*wkv.x + x.y*wkv.y + x.z*wkv.z + x.w*wkv.w;
            av[rr] += x.x*wvv.x + x.y*wvv.y + x.z*wvv.z + x.w*wvv.w;
        }
    }
    const float bqv = bq[c] + beq[c];
    const float bkv = bk[c] + bek[c];
    const float bvv = bv[c] + bev[c];
    const int h = c >> 5, d = c & 31;
    #pragma unroll
    for (int rr = 0; rr < 4; rr++) {
        const int g  = g0 + rr;
        const int bb = g >> 9, ii = g & (N_ - 1);
        size_t o = ((size_t)(bb * NH_ + h) * N_ + ii) * DH_ + d;
        Qh[o] = aq[rr] + bqv;
        Kh[o] = ak[rr] + bkv;
        Vh[o] = av[rr] + bvv;
    }
}

// ------ main kernel: block=(b,i), wave=head, wave-PRIVATE staging ------
// ZERO barriers, ZERO atomics. Each wave stages its own 16-j e-tiles into a
// private LDS ring (in-order DS ops within a wave make this race-free),
// loops all 512 j for its head, and exclusively owns its 32 output floats.
__global__ __launch_bounds__(512, 4) void attn_kernel(
    const float* __restrict__ edge,
    const float* __restrict__ Qh, const float* __restrict__ Kh,
    const float* __restrict__ Vh, const unsigned short* __restrict__ W16,
    float* __restrict__ out)
{
    __shared__ unsigned short lds_[NH_][2][16 * 72];   // per-wave ring

    const int tid  = threadIdx.x;
    const int lane = tid & 63;
    const int h    = tid >> 6;       // wave id == head
    const int q4   = lane >> 4;
    const int l15  = lane & 15;
    const int blk  = blockIdx.x;
    const int b    = blk >> 9;
    const int i    = blk & (N_ - 1);
    const int bh   = b * NH_ + h;

    // W A-operand frags: A[m=l15][k=q4*8+kk]; wf[m][half][ks]
    bf16x8 wf[3][2][2];
    #pragma unroll
    for (int m = 0; m < 3; m++)
        #pragma unroll
        for (int hf = 0; hf < 2; hf++)
            #pragma unroll
            for (int ks = 0; ks < 2; ks++)
                wf[m][hf][ks] = __builtin_bit_cast(bf16x8,
                    *reinterpret_cast<const u32x4*>(
                    W16 + m * (ND_ * ED_) + (h * DH_ + hf * 16 + l15) * ED_
                        + ks * 32 + q4 * 8));

    const float* Qrow = Qh + ((size_t)bh * N_ + i) * DH_;
    const f32x4 Cq0 = *reinterpret_cast<const f32x4*>(Qrow + q4 * 4);
    const f32x4 Cq1 = *reinterpret_cast<const f32x4*>(Qrow + 16 + q4 * 4);

    const float* Kbase = Kh + (size_t)bh * N_ * DH_;
    const float* Vbase = Vh + (size_t)bh * N_ * DH_;
    const float* ebase = edge + (size_t)blk * N_ * ED_;

    float l_acc = 0.f;
    f32x4 o0 = {0.f, 0.f, 0.f, 0.f}, o1 = {0.f, 0.f, 0.f, 0.f};
    const float scale = 0.17677669529663687f;   // 1/sqrt(32)

    // ---- stage tile 0 into ring slot 0 (wave-private; no barrier) ----
    float4 g[4];
    {
        const float4* ep = reinterpret_cast<const float4*>(ebase);
        #pragma unroll
        for (int k = 0; k < 4; k++) g[k] = ep[lane + k * 64];
        unsigned short* buf = lds_[h][0];
        #pragma unroll
        for (int k = 0; k < 4; k++) {
            const int F = lane + k * 64;          // float4 flat index 0..255
            const int row = F >> 4, c4 = F & 15;
            uint2 v = {pack_bf16(g[k].x, g[k].y), pack_bf16(g[k].z, g[k].w)};
            *reinterpret_cast<uint2*>(buf + row * 72 + c4 * 4) = v;
        }
    }

    #pragma unroll 1
    for (int t = 0; t < N_ / 16; t++) {
        if (t < 31) {   // issue next tile's global loads early
            const float4* ep = reinterpret_cast<const float4*>(ebase + (t + 1) * 1024);
            #pragma unroll
            for (int k = 0; k < 4; k++) g[k] = ep[lane + k * 64];
        }

        // e B-frags from private ring: B[k=q4*8+kk][n=j=l15]
        const unsigned short* arow = lds_[h][t & 1] + l15 * 72 + q4 * 8;
        const bf16x8 a0 = __builtin_bit_cast(bf16x8, *reinterpret_cast<const u32x4*>(arow));
        const bf16x8 a1 = __builtin_bit_cast(bf16x8, *reinterpret_cast<const u32x4*>(arow + 32));

        // K/V C-init: element (reg r, lane) = K[j=l15][(hf*16)+q4*4+r]
        const int j = t * 16 + l15;
        const float* Krow = Kbase + (size_t)j * DH_;
        const float* Vrow = Vbase + (size_t)j * DH_;
        const f32x4 Ck0 = *reinterpret_cast<const f32x4*>(Krow + q4 * 4);
        const f32x4 Ck1 = *reinterpret_cast<const f32x4*>(Krow + 16 + q4 * 4);
        const f32x4 Cv0 = *reinterpret_cast<const f32x4*>(Vrow + q4 * 4);
        const f32x4 Cv1 = *reinterpret_cast<const f32x4*>(Vrow + 16 + q4 * 4);

        f32x4 eq0 = __builtin_amdgcn_mfma_f32_16x16x32_bf16(wf[0][0][0], a0, Cq0, 0, 0, 0);
        f32x4 eq1 = __builtin_amdgcn_mfma_f32_16x16x32_bf16(wf[0][1][0], a0, Cq1, 0, 0, 0);
        f32x4 ek0 = __builtin_amdgcn_mfma_f32_16x16x32_bf16(wf[1][0][0], a0, Ck0, 0, 0, 0);
        f32x4 ek1 = __builtin_amdgcn_mfma_f32_16x16x32_bf16(wf[1][1][0], a0, Ck1, 0, 0, 0);
        f32x4 ev0 = __builtin_amdgcn_mfma_f32_16x16x32_bf16(wf[2][0][0], a0, Cv0, 0, 0, 0);
        f32x4 ev1 = __builtin_amdgcn_mfma_f32_16x16x32_bf16(wf[2][1][0], a0, Cv1, 0, 0, 0);
        eq0 = __builtin_amdgcn_mfma_f32_16x16x32_bf16(wf[0][0][1], a1, eq0, 0, 0, 0);
        eq1 = __builtin_amdgcn_mfma_f32_16x16x32_bf16(wf[0][1][1], a1, eq1, 0, 0, 0);
        ek0 = __builtin_amdgcn_mfma_f32_16x16x32_bf16(wf[1][0][1], a1, ek0, 0, 0, 0);
        ek1 = __builtin_amdgcn_mfma_f32_16x16x32_bf16(wf[1][1][1], a1, ek1, 0, 0, 0);
        ev0 = __builtin_amdgcn_mfma_f32_16x16x32_bf16(wf[2][0][1], a1, ev0, 0, 0, 0);
        ev1 = __builtin_amdgcn_mfma_f32_16x16x32_bf16(wf[2][1][1], a1, ev1, 0, 0, 0);

        // score for lane's j (reduce over d via quad shuffles), unnormalized exp
        float s = eq0[0]*ek0[0] + eq0[1]*ek0[1] + eq0[2]*ek0[2] + eq0[3]*ek0[3]
                + eq1[0]*ek1[0] + eq1[1]*ek1[1] + eq1[2]*ek1[2] + eq1[3]*ek1[3];
        s += __shfl_xor(s, 16, 64);
        s += __shfl_xor(s, 32, 64);
        const float p = __expf(fmaf(s, scale, -4.f));   // shift cancels in norm

        l_acc += p;
        o0 += ev0 * p;
        o1 += ev1 * p;

        if (t < 31) {   // pack+write next tile into the other ring slot
            unsigned short* buf = lds_[h][(t + 1) & 1];
            #pragma unroll
            for (int k = 0; k < 4; k++) {
                const int F = lane + k * 64;
                const int row = F >> 4, c4 = F & 15;
                uint2 v = {pack_bf16(g[k].x, g[k].y), pack_bf16(g[k].z, g[k].w)};
                *reinterpret_cast<uint2*>(buf + row * 72 + c4 * 4) = v;
            }
        }
    }

    // reduce over the 16 j-classes (masks 1..8 stay within each quad)
    #pragma unroll
    for (int mask = 1; mask <= 8; mask <<= 1) {
        l_acc += __shfl_xor(l_acc, mask, 64);
        #pragma unroll
        for (int r = 0; r < 4; r++) {
            o0[r] += __shfl_xor(o0[r], mask, 64);
            o1[r] += __shfl_xor(o1[r], mask, 64);
        }
    }
    const float inv = 1.f / l_acc;
    if (l15 == 0) {
        float* orow = out + (size_t)(b * N_ + i) * ND_ + h * DH_ + q4 * 4;
        float4 va = {o0[0] * inv, o0[1] * inv, o0[2] * inv, o0[3] * inv};
        float4 vb = {o1[0] * inv, o1[1] * inv, o1[2] * inv, o1[3] * inv};
        *reinterpret_cast<float4*>(orow)      = va;
        *reinterpret_cast<float4*>(orow + 16) = vb;
    }
}

extern "C" void kernel_launch(void* const* d_in, const int* in_sizes, int n_in,
                              void* d_out, int out_size, void* d_ws, size_t ws_size,
                              hipStream_t stream) {
    const float* node = (const float*)d_in[0];
    const float* edge = (const float*)d_in[1];
    const float* Wnq  = (const float*)d_in[2];
    const float* bnq  = (const float*)d_in[3];
    const float* Wnk  = (const float*)d_in[4];
    const float* bnk  = (const float*)d_in[5];
    const float* Wnv  = (const float*)d_in[6];
    const float* bnv  = (const float*)d_in[7];
    const float* Weq  = (const float*)d_in[8];
    const float* beq  = (const float*)d_in[9];
    const float* Wek  = (const float*)d_in[10];
    const float* bek  = (const float*)d_in[11];
    const float* Wev  = (const float*)d_in[12];
    const float* bev  = (const float*)d_in[13];

    char* ws = (char*)d_ws;
    unsigned short* W16 = (unsigned short*)ws;              // 96 KB
    float* Qh = (float*)(ws + 131072);
    float* Kh = Qh + (size_t)B_ * N_ * ND_;
    float* Vh = Kh + (size_t)B_ * N_ * ND_;
    float* out = (float*)d_out;

    cvt_w_kernel<<<192, 256, 0, stream>>>(Weq, Wek, Wev, W16);
    qkv_kernel<<<(B_ * N_) / 4, 256, 0, stream>>>(node, Wnq, bnq, Wnk, bnk, Wnv, bnv,
                                                  beq, bek, bev, Qh, Kh, Vh);
    attn_kernel<<<B_ * N_, 512, 0, stream>>>(edge, Qh, Kh, Vh, W16, out);
}